// Round 5
// baseline (157.394 us; speedup 1.0000x reference)
//
#include <hip/hip_runtime.h>
#include <hip/hip_bf16.h>
#include <math.h>

#define PSZ   147456           // pixels per sample (384*384)
#define NTOT  1179648          // 8 * PSZ
#define WW    384
#define HH    384
#define NIMG  8
#define NBINH 2048             // histogram bins, width 1/256, covers e in (0,8)
#define INF2F 294913.0f        // H*H + W*W + 1
#define GV    4608             // NTOT / 256
#define BPS   576              // k_fused blocks per sample (PSZ / 256)

// ---- exact, contraction-proof helpers ----
static __device__ __forceinline__ float errval(float x, float z) {
    float s = __fsub_rn(__fmul_rn(2.0f, z), 1.0f);   // exactly +-1
    return __fsub_rn(1.0f, __fmul_rn(x, s));
}
static __device__ __forceinline__ int binof(float e) {
    int b = (int)(__fmul_rn(e, 256.0f));
    return b > (NBINH - 1) ? (NBINH - 1) : b;
}
static __device__ __forceinline__ float d2f(int d) {  // exact: d<=600 -> d*d < 2^24
    return (float)(d * d);
}

// nearest set bit distance in a 384-bit row mask (600 if none)
static __device__ __forceinline__ int ndist(const unsigned long long* m, int p) {
    int q = p >> 6, b = p & 63;
    int d = 1 << 20;
    unsigned long long t = m[q] >> b;                // bits >= p (incl. self)
    if (t) d = __builtin_ctzll(t);
    else {
        for (int u = q + 1; u < 6; ++u)
            if (m[u]) { d = u * 64 + __builtin_ctzll(m[u]) - p; break; }
    }
    int dl = 1 << 20;
    unsigned long long v = m[q] << (63 - b);         // bits <= p shifted so p->63
    if (v) dl = __builtin_clzll(v);
    else {
        for (int u = q - 1; u >= 0; --u)
            if (m[u]) { dl = p - (u * 64 + 63 - __builtin_clzll(m[u])); break; }
    }
    if (dl < d) d = dl;
    return (d > 600) ? 600 : d;
}

// ---- K1: horizontal EDT via per-wave row bitmasks; packed u16 pair output ----
__global__ __launch_bounds__(256) void k_edt_h(const float* __restrict__ tgt,
                                               unsigned int* __restrict__ g2) {
    int row = blockIdx.x * 4 + (threadIdx.x >> 6);   // img*384 + i
    int l = threadIdx.x & 63;
    const float* tr = tgt + (size_t)row * WW;
    unsigned long long mf[6], mb[6];
#pragma unroll
    for (int c = 0; c < 6; ++c) {
        mf[c] = __ballot(tr[c * 64 + l] > 0.5f);     // wave-uniform row fg mask
        mb[c] = ~mf[c];
    }
    size_t ob = (size_t)row * WW;
#pragma unroll
    for (int c = 0; c < 6; ++c) {
        int p = c * 64 + l;
        g2[ob + p] = (unsigned int)ndist(mf, p) | ((unsigned int)ndist(mb, p) << 16);
    }
}

// ---- K2: fused vertical EDT (chunked early-exit) + elementwise + LDS histogram ----
__global__ __launch_bounds__(256) void k_fused(const float* __restrict__ pred,
                                               const float* __restrict__ tgt,
                                               const unsigned int* __restrict__ g2,
                                               unsigned long long* __restrict__ hist,
                                               float* __restrict__ pB, float* __restrict__ pP,
                                               float* __restrict__ pPT, float* __restrict__ pBnd,
                                               unsigned int* __restrict__ pPc,
                                               unsigned int* __restrict__ maxabsBits) {
    __shared__ unsigned long long h[NBINH * 2];      // 32 KB
    int t = threadIdx.x;
    for (int q = t; q < NBINH * 2; q += 256) h[q] = 0ull;

    int n = blockIdx.x * 256 + t;
    int rem = n % PSZ;
    int i = rem / WW;
    int j = rem - i * WW;
    const unsigned int* g2i = g2 + (size_t)(n - rem);
    unsigned int w0 = g2i[rem];
    float aF = d2f(w0 & 0xffffu);
    float aB = d2f(w0 >> 16);
    __syncthreads();                                 // hist zero done
    // vertical combine: chunks of 4 radii, one exact break test per chunk;
    // overshoot iterations are no-ops (r2 >= a  =>  fminf(a, r2+..) == a)
    for (int rc = 1; rc < HH; rc += 4) {
        if ((float)(rc * rc) >= fmaxf(aF, aB)) break;
#pragma unroll
        for (int u = 0; u < 4; ++u) {
            int r = rc + u;
            float r2 = (float)(r * r);
            int up = i - r, dn = i + r;
            if (up >= 0) {
                unsigned int wu = g2i[up * WW + j];
                aF = fminf(aF, r2 + d2f(wu & 0xffffu));
                aB = fminf(aB, r2 + d2f(wu >> 16));
            }
            if (dn < HH) {
                unsigned int wd = g2i[dn * WW + j];
                aF = fminf(aF, r2 + d2f(wd & 0xffffu));
                aB = fminf(aB, r2 + d2f(wd >> 16));
            }
        }
    }
    float x = pred[n], z = tgt[n];
    bool lab = z > 0.5f;
    float df = sqrtf(fminf(aF, INF2F));
    float db = sqrtf(fminf(aB, INF2F));
    float dv = lab ? -db : df;                       // signed, unnormalized
    float bce = fmaxf(x, 0.0f) - x * z + log1pf(expf(-fabsf(x)));
    float p = 1.0f / (1.0f + expf(-x));
    // histogram into LDS (packed u64: count<<46 | sum(e*2^24), both exact)
    float e = errval(x, z);
    if (e > 0.0f) {
        int bin = binof(e);
        unsigned long long add = (1ull << 46) |
            (unsigned long long)__fmul_rn(e, 16777216.0f);
        atomicAdd(&h[(bin << 1) + (lab ? 1 : 0)], add);
    }
    // wave butterfly reductions (fixed order -> deterministic)
    float vals[6];
    vals[0] = bce; vals[1] = p; vals[2] = lab ? p : 0.0f;
    vals[3] = p * dv; vals[4] = lab ? 1.0f : 0.0f; vals[5] = fabsf(dv);
#pragma unroll
    for (int k = 0; k < 5; ++k)
#pragma unroll
        for (int off = 32; off; off >>= 1) vals[k] += __shfl_xor(vals[k], off);
#pragma unroll
    for (int off = 32; off; off >>= 1) vals[5] = fmaxf(vals[5], __shfl_xor(vals[5], off));
    __shared__ float sw[4][6];
    int wv = t >> 6, ln = t & 63;
    if (ln == 0) {
#pragma unroll
        for (int k = 0; k < 6; ++k) sw[wv][k] = vals[k];
    }
    __syncthreads();
    if (t < 6) {
        int k = t;
        if (k == 5) {
            float a = fmaxf(fmaxf(sw[0][5], sw[1][5]), fmaxf(sw[2][5], sw[3][5]));
            atomicMax(maxabsBits, __float_as_uint(a));
        } else {
            float a = sw[0][k] + sw[1][k] + sw[2][k] + sw[3][k];
            if (k == 0) pB[blockIdx.x] = a;
            else if (k == 1) pP[blockIdx.x] = a;
            else if (k == 2) pPT[blockIdx.x] = a;
            else if (k == 3) pBnd[blockIdx.x] = a;
            else pPc[blockIdx.x] = (unsigned int)(a + 0.5f);
        }
    }
    // flush nonzero hist slots (<=256 of 4096) with deterministic integer atomics
    unsigned long long* gh = hist + ((size_t)(blockIdx.x / BPS) * NBINH << 1);
    for (int q = t; q < NBINH * 2; q += 256) {
        unsigned long long v = h[q];
        if (v) atomicAdd(&gh[q], v);
    }
}

// ---- K3: per-sample bin scan -> Lovasz via binned-tie closed form ----
__global__ __launch_bounds__(256) void k_scanlov(const unsigned long long* __restrict__ hist,
                                                 const unsigned int* __restrict__ pPc,
                                                 double* __restrict__ pLovD,
                                                 unsigned int* __restrict__ Pfin) {
    int b = blockIdx.x, t = threadIdx.x;
    __shared__ unsigned int sred[256];
    unsigned int ps = 0;
    for (int q = t; q < BPS; q += 256) ps += pPc[b * BPS + q];
    sred[t] = ps; __syncthreads();
    for (int s = 128; s > 0; s >>= 1) { if (t < s) sred[t] += sred[t + s]; __syncthreads(); }
    unsigned int Pfull = sred[0];
    if (t == 0) Pfin[b] = Pfull;
    __syncthreads();
    double P = (double)Pfull;
    const unsigned long long* hc = hist + ((size_t)b * NBINH << 1);
    __shared__ unsigned int sN[257], sP2[257];
    unsigned int ln = 0, lp = 0;
    int m0 = t * (NBINH / 256);                      // 8 bins per thread
    for (int m = m0; m < m0 + NBINH / 256; ++m) {
        ln += (unsigned int)(hc[2 * m] >> 46);
        lp += (unsigned int)(hc[2 * m + 1] >> 46);
    }
    sN[t] = ln; sP2[t] = lp;
    __syncthreads();
    if (t == 0) {
        unsigned int aN = 0, aP = 0;
        for (int q = 0; q < 256; ++q) {
            unsigned int nn = sN[q], pp = sP2[q];
            sN[q] = aN; sP2[q] = aP;
            aN += nn; aP += pp;
        }
        sN[256] = aN; sP2[256] = aP;
    }
    __syncthreads();
    unsigned int totN = sN[256], totP = sP2[256];
    unsigned int runN = sN[t], runP = sP2[t];        // counts in bins < m
    const double EPS = 1e-7;
    const double SCL = 1.0 / 16777216.0;
    const unsigned long long MSK = (1ull << 46) - 1;
    double l = 0.0;
    for (int m = m0; m < m0 + NBINH / 256; ++m) {
        unsigned long long vn = hc[2 * m], vp = hc[2 * m + 1];
        unsigned int hn = (unsigned int)(vn >> 46), hp = (unsigned int)(vp >> 46);
        if (hn | hp) {
            double negAbove = (double)(totN - runN - hn);   // negatives in higher bins
            double D0 = P + negAbove + EPS;
            if (hp) {
                double sp = (double)(vp & MSK) * SCL;
                l += sp / D0;                                // bin positives share denom
            }
            if (hn) {
                double sn = (double)(vn & MSK) * SCL;
                double pAbove = (double)(totP - runP);       // positives ranked above group
                double D1 = D0 + (double)hn;
                l += (P - pAbove) * (sn / (double)hn) * (1.0 / D0 - 1.0 / D1);
            }
            runN += hn; runP += hp;
        }
    }
    __shared__ double dred[256];
    dred[t] = l; __syncthreads();
    for (int s = 128; s > 0; s >>= 1) { if (t < s) dred[t] += dred[t + s]; __syncthreads(); }
    if (t == 0) pLovD[b] = dred[0];
}

// ---- K4: final combine (deterministic f64 reduce of partials) ----
__global__ __launch_bounds__(256) void k_final(const float* __restrict__ pB, const float* __restrict__ pP,
                                               const float* __restrict__ pPT, const float* __restrict__ pBnd,
                                               const double* __restrict__ pLovD,
                                               const unsigned int* __restrict__ Pfin,
                                               const unsigned int* __restrict__ maxabsBits,
                                               float* __restrict__ out) {
    __shared__ double red[256];
    __shared__ double res[4];
    const float* arrs[4] = {pB, pP, pPT, pBnd};
    int t = threadIdx.x;
    for (int a = 0; a < 4; ++a) {
        double sum = 0.0;
        for (int q = t; q < GV; q += 256) sum += (double)arrs[a][q];
        red[t] = sum; __syncthreads();
        for (int s = 128; s > 0; s >>= 1) { if (t < s) red[t] += red[t + s]; __syncthreads(); }
        if (t == 0) res[a] = red[0];
        __syncthreads();
    }
    if (t == 0) {
        double sumBCE = res[0], sumP = res[1], sumPT = res[2], sumBD = res[3];
        double tsum = 0.0, sumLV = 0.0;
        for (int b = 0; b < NIMG; ++b) { tsum += (double)Pfin[b]; sumLV += pLovD[b]; }
        double bce = sumBCE / (double)NTOT;
        double dice = 1.0 - (2.0 * sumPT + 1.0) / (sumP + tsum + 1.0);
        float ma = __uint_as_float(maxabsBits[0]);
        double bnd = sumBD / (double)NTOT;
        if (ma > 0.0f) bnd = bnd / (double)ma;
        double lov = sumLV / (double)NIMG;
        double loss = 0.3 * bce + 0.3 * dice + 0.2 * bnd + 0.2 * lov;
        if (loss < 0.0) loss = 0.0;
        if (loss > 100.0) loss = 100.0;
        out[0] = (float)loss;
    }
}

extern "C" void kernel_launch(void* const* d_in, const int* in_sizes, int n_in,
                              void* d_out, int out_size, void* d_ws, size_t ws_size,
                              hipStream_t stream) {
    const float* pred = (const float*)d_in[0];
    const float* tgt  = (const float*)d_in[1];
    char* ws = (char*)d_ws;

    size_t off = 0;
    unsigned long long* hist = (unsigned long long*)(ws + off); off += (size_t)NIMG * NBINH * 2 * 8; // 256 KB
    unsigned int* maxabsBits = (unsigned int*)(ws + off); off += 64;
    size_t zeroBytes = off;
    off = (off + 1023) & ~(size_t)1023;
    double* pLovD = (double*)(ws + off); off += NIMG * 8;
    unsigned int* Pfin = (unsigned int*)(ws + off); off += NIMG * 4;
    off = (off + 63) & ~(size_t)63;
    float* pB   = (float*)(ws + off); off += (size_t)GV * 4;
    float* pP   = (float*)(ws + off); off += (size_t)GV * 4;
    float* pPT  = (float*)(ws + off); off += (size_t)GV * 4;
    float* pBnd = (float*)(ws + off); off += (size_t)GV * 4;
    unsigned int* pPc = (unsigned int*)(ws + off); off += (size_t)GV * 4;
    off = (off + 1023) & ~(size_t)1023;
    unsigned int* g2 = (unsigned int*)(ws + off); off += (size_t)NIMG * PSZ * 4;
    (void)off; (void)ws_size; (void)in_sizes; (void)n_in; (void)out_size;

    hipMemsetAsync(d_ws, 0, zeroBytes, stream);
    k_edt_h<<<NIMG * HH / 4, 256, 0, stream>>>(tgt, g2);
    k_fused<<<GV, 256, 0, stream>>>(pred, tgt, g2, hist, pB, pP, pPT, pBnd, pPc, maxabsBits);
    k_scanlov<<<NIMG, 256, 0, stream>>>(hist, pPc, pLovD, Pfin);
    k_final<<<1, 256, 0, stream>>>(pB, pP, pPT, pBnd, pLovD, Pfin, maxabsBits, (float*)d_out);
}

// Round 6
// 86.791 us; speedup vs baseline: 1.8135x; 1.8135x over previous
//
#include <hip/hip_runtime.h>
#include <hip/hip_bf16.h>
#include <math.h>

#define PSZ   147456           // pixels per sample (384*384)
#define NTOT  1179648          // 8 * PSZ
#define WW    384
#define HH    384
#define NIMG  8
#define NBINH 2048             // histogram bins, width 1/256, covers e in (0,8)
#define INF2F 294913.0f        // H*H + W*W + 1
#define GF    2304             // k_fused blocks (2 pixels per thread)
#define BPS   288              // k_fused blocks per sample
#define HBLK  128              // hist blocks (16 per sample)
#define HPXB  9216             // pixels per hist block

// ---- exact, contraction-proof helpers ----
static __device__ __forceinline__ float errval(float x, float z) {
    float s = __fsub_rn(__fmul_rn(2.0f, z), 1.0f);   // exactly +-1
    return __fsub_rn(1.0f, __fmul_rn(x, s));
}
static __device__ __forceinline__ int binof(float e) {
    int b = (int)(__fmul_rn(e, 256.0f));
    return b > (NBINH - 1) ? (NBINH - 1) : b;
}
static __device__ __forceinline__ float d2f(int d) {  // exact: d<=600 -> d*d < 2^24
    return (float)(d * d);
}

// nearest set bit distance in a 384-bit row mask (600 if none)
static __device__ __forceinline__ int ndist(const unsigned long long* m, int p) {
    int q = p >> 6, b = p & 63;
    int d = 1 << 20;
    unsigned long long t = m[q] >> b;                // bits >= p (incl. self)
    if (t) d = __builtin_ctzll(t);
    else {
        for (int u = q + 1; u < 6; ++u)
            if (m[u]) { d = u * 64 + __builtin_ctzll(m[u]) - p; break; }
    }
    int dl = 1 << 20;
    unsigned long long v = m[q] << (63 - b);         // bits <= p shifted so p->63
    if (v) dl = __builtin_clzll(v);
    else {
        for (int u = q - 1; u >= 0; --u)
            if (m[u]) { dl = p - (u * 64 + 63 - __builtin_clzll(m[u])); break; }
    }
    if (dl < d) d = dl;
    return (d > 600) ? 600 : d;
}

// ---- K1: horizontal EDT via per-wave row bitmasks; packed u16 pair output ----
__global__ __launch_bounds__(256) void k_edt_h(const float* __restrict__ tgt,
                                               unsigned int* __restrict__ g2) {
    int row = blockIdx.x * 4 + (threadIdx.x >> 6);   // img*384 + i
    int l = threadIdx.x & 63;
    const float* tr = tgt + (size_t)row * WW;
    unsigned long long mf[6], mb[6];
#pragma unroll
    for (int c = 0; c < 6; ++c) {
        mf[c] = __ballot(tr[c * 64 + l] > 0.5f);     // wave-uniform row fg mask
        mb[c] = ~mf[c];
    }
    size_t ob = (size_t)row * WW;
#pragma unroll
    for (int c = 0; c < 6; ++c) {
        int p = c * 64 + l;
        g2[ob + p] = (unsigned int)ndist(mf, p) | ((unsigned int)ndist(mb, p) << 16);
    }
}

// ---- K2: fused vertical EDT (chunked early-exit, 2-pixel ILP) + elementwise ----
__global__ __launch_bounds__(256) void k_fused(const float* __restrict__ pred,
                                               const float* __restrict__ tgt,
                                               const unsigned int* __restrict__ g2,
                                               float* __restrict__ pB, float* __restrict__ pP,
                                               float* __restrict__ pPT, float* __restrict__ pBnd,
                                               unsigned int* __restrict__ pPc,
                                               unsigned int* __restrict__ maxabsBits) {
    int t = threadIdx.x;
    int img = blockIdx.x / BPS;
    int rsub = (blockIdx.x % BPS) * 256 + t;         // 0 .. PSZ/2-1
    int i1 = rsub / WW;                              // 0..191
    int j  = rsub - i1 * WW;
    int i2 = i1 + 192;
    size_t base = (size_t)img * PSZ;
    const unsigned int* g2i = g2 + base;
    int n1 = (int)base + i1 * WW + j;
    int n2 = (int)base + i2 * WW + j;
    unsigned int w1 = g2i[i1 * WW + j];
    unsigned int w2 = g2i[i2 * WW + j];
    float aF1 = d2f(w1 & 0xffffu), aB1 = d2f(w1 >> 16);
    float aF2 = d2f(w2 & 0xffffu), aB2 = d2f(w2 >> 16);
    // two independent vertical scans in flight (MLP); chunks of 4 radii,
    // one exact break test per chunk; overshoot iterations are no-ops
    for (int rc = 1; rc < HH; rc += 4) {
        float rc2 = (float)(rc * rc);
        if (rc2 >= fmaxf(fmaxf(aF1, aB1), fmaxf(aF2, aB2))) break;
#pragma unroll
        for (int u = 0; u < 4; ++u) {
            int r = rc + u;
            float r2 = (float)(r * r);
            int up1 = i1 - r, dn1 = i1 + r;
            int up2 = i2 - r, dn2 = i2 + r;
            if (up1 >= 0) {
                unsigned int w = g2i[up1 * WW + j];
                aF1 = fminf(aF1, r2 + d2f(w & 0xffffu));
                aB1 = fminf(aB1, r2 + d2f(w >> 16));
            }
            if (dn1 < HH) {
                unsigned int w = g2i[dn1 * WW + j];
                aF1 = fminf(aF1, r2 + d2f(w & 0xffffu));
                aB1 = fminf(aB1, r2 + d2f(w >> 16));
            }
            if (up2 >= 0) {
                unsigned int w = g2i[up2 * WW + j];
                aF2 = fminf(aF2, r2 + d2f(w & 0xffffu));
                aB2 = fminf(aB2, r2 + d2f(w >> 16));
            }
            if (dn2 < HH) {
                unsigned int w = g2i[dn2 * WW + j];
                aF2 = fminf(aF2, r2 + d2f(w & 0xffffu));
                aB2 = fminf(aB2, r2 + d2f(w >> 16));
            }
        }
    }
    float x1 = pred[n1], z1 = tgt[n1];
    float x2 = pred[n2], z2 = tgt[n2];
    bool lab1 = z1 > 0.5f, lab2 = z2 > 0.5f;
    float dv1 = lab1 ? -sqrtf(fminf(aB1, INF2F)) : sqrtf(fminf(aF1, INF2F));
    float dv2 = lab2 ? -sqrtf(fminf(aB2, INF2F)) : sqrtf(fminf(aF2, INF2F));
    float bce1 = fmaxf(x1, 0.0f) - x1 * z1 + log1pf(expf(-fabsf(x1)));
    float bce2 = fmaxf(x2, 0.0f) - x2 * z2 + log1pf(expf(-fabsf(x2)));
    float p1 = 1.0f / (1.0f + expf(-x1));
    float p2 = 1.0f / (1.0f + expf(-x2));
    // wave butterfly reductions (fixed order -> deterministic)
    float vals[6];
    vals[0] = bce1 + bce2;
    vals[1] = p1 + p2;
    vals[2] = (lab1 ? p1 : 0.0f) + (lab2 ? p2 : 0.0f);
    vals[3] = p1 * dv1 + p2 * dv2;
    vals[4] = (lab1 ? 1.0f : 0.0f) + (lab2 ? 1.0f : 0.0f);
    vals[5] = fmaxf(fabsf(dv1), fabsf(dv2));
#pragma unroll
    for (int k = 0; k < 5; ++k)
#pragma unroll
        for (int off = 32; off; off >>= 1) vals[k] += __shfl_xor(vals[k], off);
#pragma unroll
    for (int off = 32; off; off >>= 1) vals[5] = fmaxf(vals[5], __shfl_xor(vals[5], off));
    __shared__ float sw[4][6];
    int wv = t >> 6, ln = t & 63;
    if (ln == 0) {
#pragma unroll
        for (int k = 0; k < 6; ++k) sw[wv][k] = vals[k];
    }
    __syncthreads();
    if (t < 6) {
        int k = t;
        if (k == 5) {
            float a = fmaxf(fmaxf(sw[0][5], sw[1][5]), fmaxf(sw[2][5], sw[3][5]));
            atomicMax(maxabsBits, __float_as_uint(a));
        } else {
            float a = sw[0][k] + sw[1][k] + sw[2][k] + sw[3][k];
            if (k == 0) pB[blockIdx.x] = a;
            else if (k == 1) pP[blockIdx.x] = a;
            else if (k == 2) pPT[blockIdx.x] = a;
            else if (k == 3) pBnd[blockIdx.x] = a;
            else pPc[blockIdx.x] = (unsigned int)(a + 0.5f);
        }
    }
}

// ---- K3: LDS-aggregated error histogram (packed u64: count<<46 | sum(e*2^24)) ----
__global__ __launch_bounds__(1024) void k_hist(const float* __restrict__ pred,
                                               const float* __restrict__ tgt,
                                               unsigned long long* __restrict__ hist) {
    __shared__ unsigned long long h[NBINH * 2];      // 32 KB
    for (int q = threadIdx.x; q < NBINH * 2; q += 1024) h[q] = 0ull;
    __syncthreads();
    int base = blockIdx.x * HPXB;
#pragma unroll
    for (int it = 0; it < HPXB / 1024; ++it) {       // 9 iterations
        int n = base + it * 1024 + threadIdx.x;
        float x = pred[n], z = tgt[n];
        float e = errval(x, z);
        if (e > 0.0f) {
            int lab = (z > 0.5f) ? 1 : 0;
            int bin = binof(e);
            unsigned long long add = (1ull << 46) |
                (unsigned long long)__fmul_rn(e, 16777216.0f);
            atomicAdd(&h[(bin << 1) + lab], add);
        }
    }
    __syncthreads();
    int s = blockIdx.x >> 4;                          // 16 blocks per sample
    unsigned long long* gh = hist + ((size_t)s * NBINH << 1);
    for (int q = threadIdx.x; q < NBINH * 2; q += 1024) {
        unsigned long long v = h[q];
        if (v) atomicAdd(&gh[q], v);                  // integer add: deterministic
    }
}

// ---- K4: per-sample bin scan -> Lovasz via binned-tie closed form ----
__global__ __launch_bounds__(256) void k_scanlov(const unsigned long long* __restrict__ hist,
                                                 const unsigned int* __restrict__ pPc,
                                                 double* __restrict__ pLovD,
                                                 unsigned int* __restrict__ Pfin) {
    int b = blockIdx.x, t = threadIdx.x;
    __shared__ unsigned int sred[256];
    unsigned int ps = 0;
    for (int q = t; q < BPS; q += 256) ps += pPc[b * BPS + q];
    sred[t] = ps; __syncthreads();
    for (int s = 128; s > 0; s >>= 1) { if (t < s) sred[t] += sred[t + s]; __syncthreads(); }
    unsigned int Pfull = sred[0];
    if (t == 0) Pfin[b] = Pfull;
    __syncthreads();
    double P = (double)Pfull;
    const unsigned long long* hc = hist + ((size_t)b * NBINH << 1);
    __shared__ unsigned int sN[257], sP2[257];
    unsigned int ln = 0, lp = 0;
    int m0 = t * (NBINH / 256);                      // 8 bins per thread
    for (int m = m0; m < m0 + NBINH / 256; ++m) {
        ln += (unsigned int)(hc[2 * m] >> 46);
        lp += (unsigned int)(hc[2 * m + 1] >> 46);
    }
    sN[t] = ln; sP2[t] = lp;
    __syncthreads();
    if (t == 0) {
        unsigned int aN = 0, aP = 0;
        for (int q = 0; q < 256; ++q) {
            unsigned int nn = sN[q], pp = sP2[q];
            sN[q] = aN; sP2[q] = aP;
            aN += nn; aP += pp;
        }
        sN[256] = aN; sP2[256] = aP;
    }
    __syncthreads();
    unsigned int totN = sN[256], totP = sP2[256];
    unsigned int runN = sN[t], runP = sP2[t];        // counts in bins < m
    const double EPS = 1e-7;
    const double SCL = 1.0 / 16777216.0;
    const unsigned long long MSK = (1ull << 46) - 1;
    double l = 0.0;
    for (int m = m0; m < m0 + NBINH / 256; ++m) {
        unsigned long long vn = hc[2 * m], vp = hc[2 * m + 1];
        unsigned int hn = (unsigned int)(vn >> 46), hp = (unsigned int)(vp >> 46);
        if (hn | hp) {
            double negAbove = (double)(totN - runN - hn);   // negatives in higher bins
            double D0 = P + negAbove + EPS;
            if (hp) {
                double sp = (double)(vp & MSK) * SCL;
                l += sp / D0;                                // bin positives share denom
            }
            if (hn) {
                double sn = (double)(vn & MSK) * SCL;
                double pAbove = (double)(totP - runP);       // positives ranked above group
                double D1 = D0 + (double)hn;
                l += (P - pAbove) * (sn / (double)hn) * (1.0 / D0 - 1.0 / D1);
            }
            runN += hn; runP += hp;
        }
    }
    __shared__ double dred[256];
    dred[t] = l; __syncthreads();
    for (int s = 128; s > 0; s >>= 1) { if (t < s) dred[t] += dred[t + s]; __syncthreads(); }
    if (t == 0) pLovD[b] = dred[0];
}

// ---- K5: final combine (deterministic f64 reduce of partials) ----
__global__ __launch_bounds__(256) void k_final(const float* __restrict__ pB, const float* __restrict__ pP,
                                               const float* __restrict__ pPT, const float* __restrict__ pBnd,
                                               const double* __restrict__ pLovD,
                                               const unsigned int* __restrict__ Pfin,
                                               const unsigned int* __restrict__ maxabsBits,
                                               float* __restrict__ out) {
    __shared__ double red[256];
    __shared__ double res[4];
    const float* arrs[4] = {pB, pP, pPT, pBnd};
    int t = threadIdx.x;
    for (int a = 0; a < 4; ++a) {
        double sum = 0.0;
        for (int q = t; q < GF; q += 256) sum += (double)arrs[a][q];
        red[t] = sum; __syncthreads();
        for (int s = 128; s > 0; s >>= 1) { if (t < s) red[t] += red[t + s]; __syncthreads(); }
        if (t == 0) res[a] = red[0];
        __syncthreads();
    }
    if (t == 0) {
        double sumBCE = res[0], sumP = res[1], sumPT = res[2], sumBD = res[3];
        double tsum = 0.0, sumLV = 0.0;
        for (int b = 0; b < NIMG; ++b) { tsum += (double)Pfin[b]; sumLV += pLovD[b]; }
        double bce = sumBCE / (double)NTOT;
        double dice = 1.0 - (2.0 * sumPT + 1.0) / (sumP + tsum + 1.0);
        float ma = __uint_as_float(maxabsBits[0]);
        double bnd = sumBD / (double)NTOT;
        if (ma > 0.0f) bnd = bnd / (double)ma;
        double lov = sumLV / (double)NIMG;
        double loss = 0.3 * bce + 0.3 * dice + 0.2 * bnd + 0.2 * lov;
        if (loss < 0.0) loss = 0.0;
        if (loss > 100.0) loss = 100.0;
        out[0] = (float)loss;
    }
}

extern "C" void kernel_launch(void* const* d_in, const int* in_sizes, int n_in,
                              void* d_out, int out_size, void* d_ws, size_t ws_size,
                              hipStream_t stream) {
    const float* pred = (const float*)d_in[0];
    const float* tgt  = (const float*)d_in[1];
    char* ws = (char*)d_ws;

    size_t off = 0;
    unsigned long long* hist = (unsigned long long*)(ws + off); off += (size_t)NIMG * NBINH * 2 * 8; // 256 KB
    unsigned int* maxabsBits = (unsigned int*)(ws + off); off += 64;
    size_t zeroBytes = off;
    off = (off + 1023) & ~(size_t)1023;
    double* pLovD = (double*)(ws + off); off += NIMG * 8;
    unsigned int* Pfin = (unsigned int*)(ws + off); off += NIMG * 4;
    off = (off + 63) & ~(size_t)63;
    float* pB   = (float*)(ws + off); off += (size_t)GF * 4;
    float* pP   = (float*)(ws + off); off += (size_t)GF * 4;
    float* pPT  = (float*)(ws + off); off += (size_t)GF * 4;
    float* pBnd = (float*)(ws + off); off += (size_t)GF * 4;
    unsigned int* pPc = (unsigned int*)(ws + off); off += (size_t)GF * 4;
    off = (off + 1023) & ~(size_t)1023;
    unsigned int* g2 = (unsigned int*)(ws + off); off += (size_t)NIMG * PSZ * 4;
    (void)off; (void)ws_size; (void)in_sizes; (void)n_in; (void)out_size;

    hipMemsetAsync(d_ws, 0, zeroBytes, stream);
    k_edt_h<<<NIMG * HH / 4, 256, 0, stream>>>(tgt, g2);
    k_fused<<<GF, 256, 0, stream>>>(pred, tgt, g2, pB, pP, pPT, pBnd, pPc, maxabsBits);
    k_hist<<<HBLK, 1024, 0, stream>>>(pred, tgt, hist);
    k_scanlov<<<NIMG, 256, 0, stream>>>(hist, pPc, pLovD, Pfin);
    k_final<<<1, 256, 0, stream>>>(pB, pP, pPT, pBnd, pLovD, Pfin, maxabsBits, (float*)d_out);
}